// Round 13
// baseline (91.771 us; speedup 1.0000x reference)
//
#include <hip/hip_runtime.h>
#include <math.h>

#define NBOX 4096
#define TILE 32
#define NT (NBOX / TILE)               // 128
#define NBLK (NT * (NT + 1) / 2)       // 8256 upper-triangle tiles, 1 wave each
#define SS 12                          // struct stride in floats (48 B, 16B-aligned)
#define JB 400                         // J region base (I region = 396 floats, padded)

typedef float v2f __attribute__((ext_vector_type(2)));
typedef float vf4 __attribute__((ext_vector_type(4)));

// LDS per-box layout (10 used floats, stride 12), packed for v_pk_fma_f32:
// [0]a0x [1]a1x [2]a0y [3]a1y | [4]sc0 [5]sc1 [6]l0 [7]l1 | [8]cx [9]cy

struct Box {
    v2f A0, A1, SC, LL;
    float cx, cy;
};

__device__ __forceinline__ float rcp_fast(float x) { return __builtin_amdgcn_rcpf(x); }
__device__ __forceinline__ v2f splat(float s) { return (v2f){s, s}; }
__device__ __forceinline__ v2f fma2(v2f a, v2f b, v2f c) { return __builtin_elementwise_fma(a, b, c); }
__device__ __forceinline__ v2f abs2(v2f a) { return __builtin_elementwise_abs(a); }

// Exact identities: overlap r = min(H1, H2, (H1+H2)/2 - |D|)  (signed)
//                   giou1d  g = r / (H1 + H2 - r)             (denom > 0)
// Math byte-identical to rounds 8-12 (absmax must stay 0.00390625).
__device__ __forceinline__ float mgiou_pair(const Box& I, const Box& J) {
    v2f dA = fma2(I.A0, splat(J.A0.x), I.A1 * J.A1.x);   // (d00, d10)
    v2f dB = fma2(I.A0, splat(J.A0.y), I.A1 * J.A1.y);   // (d01, d11)
    v2f DI = fma2(I.A0, splat(J.cx), fma2(I.A1, splat(J.cy), -I.SC));
    v2f DJ = fma2(J.A0, splat(I.cx), fma2(J.A1, splat(I.cy), -J.SC));
    v2f aA = abs2(dA), aB = abs2(dB);
    v2f HI = aA + aB;
    float HJ0 = aA.x + aA.y;
    float HJ1 = aB.x + aB.y;
    v2f SI = I.LL + HI;
    float SJ0 = J.LL.x + HJ0, SJ1 = J.LL.y + HJ1;
    v2f uI = fma2(splat(0.5f), SI, -abs2(DI));
    float uJ0 = fmaf(0.5f, SJ0, -fabsf(DJ.x));
    float uJ1 = fmaf(0.5f, SJ1, -fabsf(DJ.y));
    float r0 = fminf(fminf(I.LL.x, HI.x), uI.x);
    float r1 = fminf(fminf(I.LL.y, HI.y), uI.y);
    float r2 = fminf(fminf(J.LL.x, HJ0), uJ0);
    float r3 = fminf(fminf(J.LL.y, HJ1), uJ1);
    float g0 = r0 * rcp_fast(SI.x - r0);
    float g1 = r1 * rcp_fast(SI.y - r1);
    float g2 = r2 * rcp_fast(SJ0 - r2);
    float g3 = r3 * rcp_fast(SJ1 - r3);
    float g = fminf(fminf(g0, g1), fminf(g2, g3));
    return fmaxf(g, 0.0f);
}

// Cumulative swizzle (+4 floats per 8-struct octet, monotone, no overlap).
// b128 read cosets for 4t, t=0..7: {0,16,4,20,8,24,12,28} — all distinct,
// each address read by 8 lanes (broadcast) -> conflict-free.
__device__ __forceinline__ int sw_offset(int i) { return i * SS + (i >> 3) * 4; }

__device__ __forceinline__ Box load_box(const float* p) {
    Box b;
    float4 x = *(const float4*)(p);
    float4 y = *(const float4*)(p + 4);
    float2 z = *(const float2*)(p + 8);
    b.A0 = (v2f){x.x, x.y}; b.A1 = (v2f){x.z, x.w};
    b.SC = (v2f){y.x, y.y}; b.LL = (v2f){y.z, y.w};
    b.cx = z.x; b.cy = z.y;
    return b;
}

// ROUND 13: fine-grained PINNED store interleave. R8-R12 established
// K = C + W strictly additive (zero compute/write overlap): waves run
// identical code, hit their store bursts synchronously, backpressure the
// write path (in-order store issue parks the wave), then all resume while
// HBM idles. This round emits stores at the average rate: per kk-quarter,
// 1 vf4 upper-row store + 4 scalar mirror stores, pinned in place with
// sched_barrier(0) so the compiler cannot sink/cluster them.
__global__ __launch_bounds__(64)
void pairwise_kernel(const float* __restrict__ boxes, float* __restrict__ out) {
    // decode (bi, bj), bi <= bj, row-major over the upper triangle
    int k = blockIdx.x;
    int bi = (int)((float)(2 * NT + 1 - sqrtf((float)((2 * NT + 1) * (2 * NT + 1) - 8 * k))) * 0.5f);
    if (bi > 0 && k < bi * NT - bi * (bi - 1) / 2) bi--;
    if (k >= (bi + 1) * NT - (bi + 1) * bi / 2) bi++;
    int bj = bi + (k - (bi * NT - bi * (bi - 1) / 2));

    __shared__ float sm[JB + 400];      // 32 I structs @0, 32 J structs @JB (swizzled)

    int tid = threadIdx.x;
    {   // fused precompute: 64 threads each build one box struct
        int loc = tid & (TILE - 1);
        int box = ((tid < TILE) ? bi : bj) * TILE + loc;
        float cx = boxes[box * 5 + 0];
        float cy = boxes[box * 5 + 1];
        float w  = boxes[box * 5 + 2];
        float h  = boxes[box * 5 + 3];
        float ang = boxes[box * 5 + 4];
        float s, c;
        __sincosf(ang, &s, &c);
        float a0x = w * c, a0y = -w * s;    // full edge vectors (match ref rot)
        float a1x = h * s, a1y =  h * c;
        float sc0 = fmaf(a0x, cx, a0y * cy);
        float sc1 = fmaf(a1x, cx, a1y * cy);
        float* d = &sm[((tid < TILE) ? 0 : JB) + sw_offset(loc)];
        ((float4*)d)[0] = make_float4(a0x, a1x, a0y, a1y);
        ((float4*)d)[1] = make_float4(sc0, sc1, w * w, h * h);
        ((float2*)d)[4] = make_float2(cx, cy);
    }
    __syncthreads();

    int tx = tid & 7;           // j quad: 4tx .. 4tx+3   (32 cols)
    int ty = tid >> 3;          // i quad: 4ty .. 4ty+3   (32 rows)
    Box J[4];
    const float* jp = &sm[JB + sw_offset(4 * tx)];   // 4tx..4tx+3 in one octet
    #pragma unroll
    for (int m = 0; m < 4; ++m) J[m] = load_box(jp + m * SS);

    int ibase = bi * TILE, jbase = bj * TILE;
    bool offdiag = (bi != bj);
    const float* ip = &sm[sw_offset(4 * ty)];

    #pragma unroll
    for (int kk = 0; kk < 4; ++kk) {
        Box I = load_box(ip + kk * SS);
        int ig = ibase + 4 * ty + kk;
        float v[4];
        #pragma unroll
        for (int m = 0; m < 4; ++m) {
            int jg = jbase + 4 * tx + m;
            v[m] = (ig == jg) ? 0.0f : mgiou_pair(I, J[m]);
        }
        // upper row: 8 lanes x 16 B = 128 B contiguous per i-row
        vf4 o = {v[0], v[1], v[2], v[3]};
        *(vf4*)&out[(size_t)ig * NBOX + jbase + 4 * tx] = o;
        if (offdiag) {
            // mirror partials: 4 scalar dwords now, instead of a vf4 burst at
            // block end. Each 128B mirror line gets 4 partial writes that
            // merge in L2 (4 KB footprint stays resident across the block).
            #pragma unroll
            for (int m = 0; m < 4; ++m)
                out[(size_t)(jbase + 4 * tx + m) * NBOX + ig] = v[m];
        }
        // pin: forbid sinking/clustering the stores across kk iterations
        __builtin_amdgcn_sched_barrier(0);
    }
}

extern "C" void kernel_launch(void* const* d_in, const int* in_sizes, int n_in,
                              void* d_out, int out_size, void* d_ws, size_t ws_size,
                              hipStream_t stream) {
    const float* boxes = (const float*)d_in[0];
    float* out = (float*)d_out;
    pairwise_kernel<<<dim3(NBLK), dim3(64), 0, stream>>>(boxes, out);
}

// Round 14
// 81.322 us; speedup vs baseline: 1.1285x; 1.1285x over previous
//
#include <hip/hip_runtime.h>
#include <math.h>

#define NBOX 4096
#define TILE 32
#define NT (NBOX / TILE)               // 128
#define NBLK (NT * (NT + 1) / 2)       // 8256 upper-triangle tiles, 1 wave each
#define SS 12                          // struct stride in floats (48 B, 16B-aligned)
#define JB 400                         // J region base (I region = 396 floats, padded)

typedef float v2f __attribute__((ext_vector_type(2)));
typedef float vf4 __attribute__((ext_vector_type(4)));

// LDS per-box layout (10 used floats, stride 12), packed for v_pk_fma_f32:
// [0]a0x [1]a1x [2]a0y [3]a1y | [4]sc0 [5]sc1 [6]l0 [7]l1 | [8]cx [9]cy

struct Box {
    v2f A0, A1, SC, LL;
    float cx, cy;
};

__device__ __forceinline__ float rcp_fast(float x) { return __builtin_amdgcn_rcpf(x); }
__device__ __forceinline__ v2f splat(float s) { return (v2f){s, s}; }
__device__ __forceinline__ v2f fma2(v2f a, v2f b, v2f c) { return __builtin_elementwise_fma(a, b, c); }
__device__ __forceinline__ v2f abs2(v2f a) { return __builtin_elementwise_abs(a); }

// Exact identities: overlap r = min(H1, H2, (H1+H2)/2 - |D|)  (signed)
//                   giou1d  g = r / (H1 + H2 - r)             (denom > 0)
__device__ __forceinline__ float mgiou_pair(const Box& I, const Box& J) {
    v2f dA = fma2(I.A0, splat(J.A0.x), I.A1 * J.A1.x);   // (d00, d10)
    v2f dB = fma2(I.A0, splat(J.A0.y), I.A1 * J.A1.y);   // (d01, d11)
    v2f DI = fma2(I.A0, splat(J.cx), fma2(I.A1, splat(J.cy), -I.SC));
    v2f DJ = fma2(J.A0, splat(I.cx), fma2(J.A1, splat(I.cy), -J.SC));
    v2f aA = abs2(dA), aB = abs2(dB);
    v2f HI = aA + aB;
    float HJ0 = aA.x + aA.y;
    float HJ1 = aB.x + aB.y;
    v2f SI = I.LL + HI;
    float SJ0 = J.LL.x + HJ0, SJ1 = J.LL.y + HJ1;
    v2f uI = fma2(splat(0.5f), SI, -abs2(DI));
    float uJ0 = fmaf(0.5f, SJ0, -fabsf(DJ.x));
    float uJ1 = fmaf(0.5f, SJ1, -fabsf(DJ.y));
    float r0 = fminf(fminf(I.LL.x, HI.x), uI.x);
    float r1 = fminf(fminf(I.LL.y, HI.y), uI.y);
    float r2 = fminf(fminf(J.LL.x, HJ0), uJ0);
    float r3 = fminf(fminf(J.LL.y, HJ1), uJ1);
    float g0 = r0 * rcp_fast(SI.x - r0);
    float g1 = r1 * rcp_fast(SI.y - r1);
    float g2 = r2 * rcp_fast(SJ0 - r2);
    float g3 = r3 * rcp_fast(SJ1 - r3);
    float g = fminf(fminf(g0, g1), fminf(g2, g3));
    return fmaxf(g, 0.0f);
}

// Cumulative swizzle (+4 floats per 8-struct octet, monotone, no overlap).
// b128 read cosets for 4t, t=0..7: {0,16,4,20,8,24,12,28} — all distinct,
// each address read by 8 lanes (broadcast) -> conflict-free.
__device__ __forceinline__ int sw_offset(int i) { return i * SS + (i >> 3) * 4; }

__device__ __forceinline__ Box load_box(const float* p) {
    Box b;
    float4 x = *(const float4*)(p);
    float4 y = *(const float4*)(p + 4);
    float2 z = *(const float2*)(p + 8);
    b.A0 = (v2f){x.x, x.y}; b.A1 = (v2f){x.z, x.w};
    b.SC = (v2f){y.x, y.y}; b.LL = (v2f){y.z, y.w};
    b.cx = z.x; b.cy = z.y;
    return b;
}

// FINAL (revert to round-12 best, 81.66 us): 1-wave workgroups, 32x32
// upper-triangle tiles, symmetric mirror via direct 128B-contiguous float4
// stores. Model: kernel = 6.6 us compute + 11.3 us write (write at the
// harness-fill's own 5.9 TB/s ceiling); overlap mechanisms falsified in
// R7/R9/R10/R12/R13 — C+W additive is structural here.
__global__ __launch_bounds__(64)
void pairwise_kernel(const float* __restrict__ boxes, float* __restrict__ out) {
    // decode (bi, bj), bi <= bj, row-major over the upper triangle
    int k = blockIdx.x;
    int bi = (int)((float)(2 * NT + 1 - sqrtf((float)((2 * NT + 1) * (2 * NT + 1) - 8 * k))) * 0.5f);
    if (bi > 0 && k < bi * NT - bi * (bi - 1) / 2) bi--;
    if (k >= (bi + 1) * NT - (bi + 1) * bi / 2) bi++;
    int bj = bi + (k - (bi * NT - bi * (bi - 1) / 2));

    __shared__ float sm[JB + 400];      // 32 I structs @0, 32 J structs @JB (swizzled)

    int tid = threadIdx.x;
    {   // fused precompute: 64 threads each build one box struct
        int loc = tid & (TILE - 1);
        int box = ((tid < TILE) ? bi : bj) * TILE + loc;
        float cx = boxes[box * 5 + 0];
        float cy = boxes[box * 5 + 1];
        float w  = boxes[box * 5 + 2];
        float h  = boxes[box * 5 + 3];
        float ang = boxes[box * 5 + 4];
        float s, c;
        __sincosf(ang, &s, &c);
        float a0x = w * c, a0y = -w * s;    // full edge vectors (match ref rot)
        float a1x = h * s, a1y =  h * c;
        float sc0 = fmaf(a0x, cx, a0y * cy);
        float sc1 = fmaf(a1x, cx, a1y * cy);
        float* d = &sm[((tid < TILE) ? 0 : JB) + sw_offset(loc)];
        ((float4*)d)[0] = make_float4(a0x, a1x, a0y, a1y);
        ((float4*)d)[1] = make_float4(sc0, sc1, w * w, h * h);
        ((float2*)d)[4] = make_float2(cx, cy);
    }
    __syncthreads();

    int tx = tid & 7;           // j quad: 4tx .. 4tx+3   (32 cols)
    int ty = tid >> 3;          // i quad: 4ty .. 4ty+3   (32 rows)
    Box J[4];
    const float* jp = &sm[JB + sw_offset(4 * tx)];   // 4tx..4tx+3 in one octet
    #pragma unroll
    for (int m = 0; m < 4; ++m) J[m] = load_box(jp + m * SS);

    int ibase = bi * TILE, jbase = bj * TILE;
    bool offdiag = (bi != bj);
    const float* ip = &sm[sw_offset(4 * ty)];
    float vT[4][4];             // vT[m][kk] for the mirror stores

    #pragma unroll
    for (int kk = 0; kk < 4; ++kk) {
        Box I = load_box(ip + kk * SS);
        int ig = ibase + 4 * ty + kk;
        float v[4];
        #pragma unroll
        for (int m = 0; m < 4; ++m) {
            int jg = jbase + 4 * tx + m;
            v[m] = (ig == jg) ? 0.0f : mgiou_pair(I, J[m]);
            vT[m][kk] = v[m];
        }
        // upper tile: per instr, 8 i-rows x (8 lanes x 16 B = 128 B contiguous)
        vf4 o = {v[0], v[1], v[2], v[3]};
        *(vf4*)&out[(size_t)ig * NBOX + jbase + 4 * tx] = o;
    }

    if (offdiag) {
        // mirror tile: per instr, 8 j-rows x (8 ty-lanes x 16 B = 128 B contiguous)
        #pragma unroll
        for (int m = 0; m < 4; ++m) {
            int jg = jbase + 4 * tx + m;
            vf4 o = {vT[m][0], vT[m][1], vT[m][2], vT[m][3]};
            *(vf4*)&out[(size_t)jg * NBOX + ibase + 4 * ty] = o;
        }
    }
}

extern "C" void kernel_launch(void* const* d_in, const int* in_sizes, int n_in,
                              void* d_out, int out_size, void* d_ws, size_t ws_size,
                              hipStream_t stream) {
    const float* boxes = (const float*)d_in[0];
    float* out = (float*)d_out;
    pairwise_kernel<<<dim3(NBLK), dim3(64), 0, stream>>>(boxes, out);
}